// Round 5
// baseline (403.747 us; speedup 1.0000x reference)
//
#include <hip/hip_runtime.h>
#include <stdint.h>

#define S_LEN 2048
#define BATCH 8
#define EMB   1024
#define GAMMA 0.5f

typedef unsigned short ushort_t;
typedef __attribute__((ext_vector_type(8))) short  short8;
typedef __attribute__((ext_vector_type(8))) unsigned short ushort8;
typedef __attribute__((ext_vector_type(4))) float  floatx4;

__device__ __forceinline__ ushort_t f2bf(float f) {
  uint32_t x = __float_as_uint(f);
  x += 0x7fffu + ((x >> 16) & 1u);   // round-to-nearest-even
  return (ushort_t)(x >> 16);
}

__device__ __forceinline__ void gl_lds16(const ushort_t* g, ushort_t* l) {
  __builtin_amdgcn_global_load_lds(
      (const __attribute__((address_space(1))) unsigned int*)g,
      (__attribute__((address_space(3))) unsigned int*)l, 16, 0, 0);
}

// ---------------------------------------------------------------------------
// 256x256-tile 8-wave pipelined NT bf16 GEMM core (C = A * B^T, K-contig).
// BK=64 as two 32-wide kslices; LDS regions (ushort offsets, per buffer):
//   As0 +0 | As1 +8192 | Bs0 +16384 | Bs1 +24576 ; regions 256r x 32 bf16.
// Double buffered = 128 KiB. Swizzle: slot ^= (row>>1)&3 on both the
// pre-swizzled global source and the ds_read address (R3, conflict-free).
//
// R5: TWO intervals per K-tile (32-MFMA bursts), reads issued at interval
// top so they drain under the burst; stages next so VMEM latency is covered
// by the burst; single vmcnt(4) per interval. 2 barriers/K-tile (was 4).
//   J_0(kt): bar; lgkm0; read {ar2 x8, u0,u1,v0,v1} from cur s1-regions;
//            stage As1,Bs1(kt+1)->nxt; MFMA s0 x nf0..3 (32); vmcnt(4)
//   J_1(kt): bar; lgkm0; read {ar x8, b0,b1,t0,t1} from nxt s0-regions;
//            stage As0,Bs0(kt+2)->cur; MFMA s1 x nf0..3 (32); vmcnt(4|0)
// Ledger (loads): J_0 stages 4 on top of As0Bs0(kt+1)[4] -> vmcnt(4) drains
// the older pair (J_1's nxt reads safe after the following barrier).
// J_1 stages 4 on top of As1Bs1(kt+1)[4] -> vmcnt(4) drains it for
// J_0(kt+1). Write-after-read: every stage is issued >=1 barrier after its
// region's readers' lgkm0 drain (t0/t1 are read in J_1(kt-1), NOT J_0(kt),
// exactly so the J_1(kt) stage of Bs0(kt+2) has one-barrier separation).
// ---------------------------------------------------------------------------

__device__ __forceinline__ void stage_half(const ushort_t* __restrict__ G,
                                           int ld, int kcol,
                                           ushort_t* lregion, int wave, int lane) {
  const int r4 = lane >> 2;
  const int slot = (lane & 3) ^ ((r4 >> 1) & 3);    // source pre-swizzle
  const ushort_t* g = G + (size_t)(wave * 32 + r4) * ld + kcol + slot * 8;
  gl_lds16(g, lregion + wave * 1024);
  gl_lds16(g + (size_t)16 * ld, lregion + wave * 1024 + 512);
}

__device__ __forceinline__ short8 lds_frag(const ushort_t* region, int row, int q) {
  return *(const short8*)(region + row * 32 + (((q ^ (row >> 1)) & 3) << 3));
}

#define MFMA_16(AR, B0, B1, J0, J1)                                            \
  _Pragma("unroll")                                                            \
  for (int i = 0; i < 8; ++i) {                                                \
    acc[i][J0] = __builtin_amdgcn_mfma_f32_16x16x32_bf16(AR[i], B0, acc[i][J0], 0, 0, 0); \
    acc[i][J1] = __builtin_amdgcn_mfma_f32_16x16x32_bf16(AR[i], B1, acc[i][J1], 0, 0, 0); \
  }

#define INTERVAL_OPEN()                                                        \
  __builtin_amdgcn_s_barrier();                                                \
  asm volatile("s_waitcnt lgkmcnt(0)" ::: "memory");                           \
  __builtin_amdgcn_sched_barrier(0);

__device__ __forceinline__ void gemm8_core(
    const ushort_t* __restrict__ A, const ushort_t* __restrict__ B,
    int lda, int ldb, int K, ushort_t* smem, floatx4 (&acc)[8][4])
{
  const int tid = threadIdx.x;
  const int wave = tid >> 6, lane = tid & 63;
  const int wm = wave >> 2, wn = wave & 3;      // 2 (M) x 4 (N) wave grid
  const int lr = lane & 15, q = lane >> 4;
  const int NT = K >> 6;
  const int ra = wm * 128 + lr;   // wave's A-row base
  const int rb = wn * 64 + lr;    // wave's B-row base

  // Prologue: stage As0Bs0(0), As1Bs1(0), As0Bs0(1) = 12 loads.
  stage_half(A, lda, 0,  smem +     0, wave, lane);   // As0(0)
  stage_half(B, ldb, 0,  smem + 16384, wave, lane);   // Bs0(0)
  stage_half(A, lda, 32, smem +  8192, wave, lane);   // As1(0)
  stage_half(B, ldb, 32, smem + 24576, wave, lane);   // Bs1(0)
  stage_half(A, lda, 64, smem + 32768, wave, lane);   // As0(1)
  stage_half(B, ldb, 64, smem + 49152, wave, lane);   // Bs0(1)
  asm volatile("s_waitcnt vmcnt(4)" ::: "memory");    // As0Bs0(0)+As1Bs1(0) landed
  __builtin_amdgcn_s_barrier();
  __builtin_amdgcn_sched_barrier(0);

  short8 ar[8], ar2[8], b0, b1, t0, t1, u0, u1, v0, v1;
  // prologue reads: full s0 operand set for J_0(0)
#pragma unroll
  for (int i = 0; i < 8; ++i) ar[i] = lds_frag(smem, ra + i * 16, q);
  b0 = lds_frag(smem + 16384, rb,      q);
  b1 = lds_frag(smem + 16384, rb + 16, q);
  t0 = lds_frag(smem + 16384, rb + 32, q);
  t1 = lds_frag(smem + 16384, rb + 48, q);

  for (int kt = 0; kt < NT; ++kt) {
    ushort_t* const cur = smem + (kt & 1) * 32768;
    ushort_t* const nxt = smem + ((kt & 1) ^ 1) * 32768;
    const bool s1 = (kt + 1) < NT, s2 = (kt + 2) < NT;

    // ---- J_0: reads for J_1 (cur s1), stage As1/Bs1(kt+1), MFMA s0 x 32
    INTERVAL_OPEN()
#pragma unroll
    for (int i = 0; i < 8; ++i) ar2[i] = lds_frag(cur + 8192, ra + i * 16, q);
    u0 = lds_frag(cur + 24576, rb,      q);
    u1 = lds_frag(cur + 24576, rb + 16, q);
    v0 = lds_frag(cur + 24576, rb + 32, q);
    v1 = lds_frag(cur + 24576, rb + 48, q);
    if (s1) {
      stage_half(A, lda, (kt + 1) * 64 + 32, nxt +  8192, wave, lane);  // As1(kt+1)
      stage_half(B, ldb, (kt + 1) * 64 + 32, nxt + 24576, wave, lane);  // Bs1(kt+1)
    }
    __builtin_amdgcn_s_setprio(1);
    MFMA_16(ar, b0, b1, 0, 1)
    MFMA_16(ar, t0, t1, 2, 3)
    __builtin_amdgcn_s_setprio(0);
    if (s1) { asm volatile("s_waitcnt vmcnt(4)" ::: "memory"); }

    // ---- J_1: reads for J_0(kt+1) (nxt s0), stage As0/Bs0(kt+2), MFMA s1 x 32
    INTERVAL_OPEN()
    if (s1) {
#pragma unroll
      for (int i = 0; i < 8; ++i) ar[i] = lds_frag(nxt, ra + i * 16, q);
      b0 = lds_frag(nxt + 16384, rb,      q);
      b1 = lds_frag(nxt + 16384, rb + 16, q);
      t0 = lds_frag(nxt + 16384, rb + 32, q);
      t1 = lds_frag(nxt + 16384, rb + 48, q);
    }
    if (s2) {
      stage_half(A, lda, (kt + 2) * 64, cur,         wave, lane);  // As0(kt+2)
      stage_half(B, ldb, (kt + 2) * 64, cur + 16384, wave, lane);  // Bs0(kt+2)
    }
    __builtin_amdgcn_s_setprio(1);
    MFMA_16(ar2, u0, u1, 0, 1)
    MFMA_16(ar2, v0, v1, 2, 3)
    __builtin_amdgcn_s_setprio(0);
    if (s2)      { asm volatile("s_waitcnt vmcnt(4)" ::: "memory"); }
    else if (s1) { asm volatile("s_waitcnt vmcnt(0)" ::: "memory"); }
  }
}

// ---------- quantize / pack ----------
__global__ __launch_bounds__(256) void k_quant_x(const float* __restrict__ X,
                                                 ushort_t* __restrict__ Xb) {
  size_t i = ((size_t)blockIdx.x * 256 + threadIdx.x) * 4;
  float4 v = *(const float4*)(X + i);
  *(ushort4*)(Xb + i) = make_ushort4(f2bf(v.x), f2bf(v.y), f2bf(v.z), f2bf(v.w));
}

__global__ __launch_bounds__(256) void k_quant_w(
    const float* __restrict__ Wq, const float* __restrict__ Wk,
    const float* __restrict__ Wv, ushort_t* __restrict__ W) {
  size_t i = ((size_t)blockIdx.x * 256 + threadIdx.x) * 4;
  int row = (int)(i >> 10), col = (int)(i & 1023);
  int sel = row >> 10, sr = row & 1023;
  const float* src = sel == 0 ? Wq : (sel == 1 ? Wk : Wv);
  float4 v = *(const float4*)(src + (size_t)sr * 1024 + col);
  *(ushort4*)(W + i) = make_ushort4(f2bf(v.x), f2bf(v.y), f2bf(v.z), f2bf(v.w));
}

__global__ __launch_bounds__(256) void k_bias_zero(
    const float* __restrict__ bq, const float* __restrict__ bk,
    const float* __restrict__ bv, float* __restrict__ bias,
    float* __restrict__ q2, float* __restrict__ k2, float* __restrict__ rsum) {
  int i = blockIdx.x * 256 + threadIdx.x;
  if (i < 1024)       bias[i] = bq[i];
  else if (i < 2048)  bias[i] = bk[i - 1024];
  else if (i < 3072)  bias[i] = bv[i - 2048];
  if (i < BATCH * S_LEN) { q2[i] = 0.f; k2[i] = 0.f; rsum[i] = 0.f; }
}

// ---------- GEMM 1: QKV projection (M=16384, N=3072, K=1024) ----------
__global__ __launch_bounds__(512, 2) void k_gemm_qkv(
    const ushort_t* __restrict__ Xb, const ushort_t* __restrict__ W,
    const float* __restrict__ bias,
    ushort_t* __restrict__ Q, ushort_t* __restrict__ Kp, ushort_t* __restrict__ V,
    float* __restrict__ q2, float* __restrict__ k2) {
  __shared__ __attribute__((aligned(16))) ushort_t smem[65536];
  const int mt = blockIdx.x * 256, nt = blockIdx.y * 256;
  floatx4 acc[8][4];
  const floatx4 z = {0.f, 0.f, 0.f, 0.f};
#pragma unroll
  for (int i = 0; i < 8; ++i)
#pragma unroll
    for (int j = 0; j < 4; ++j) acc[i][j] = z;

  gemm8_core(Xb + (size_t)mt * EMB, W + (size_t)nt * EMB, EMB, EMB, EMB, smem, acc);

  const int lane = threadIdx.x & 63, wave = threadIdx.x >> 6;
  const int wm = wave >> 2, wn = wave & 3;
  const int lr = lane & 15, q = lane >> 4;
  const int which = nt >> 10;        // 0=q 1=k 2=v  (256 | 1024 so no straddle)
  const int nc0 = nt & 1023;
  ushort_t* dst = which == 0 ? Q : (which == 1 ? Kp : V);
  float* sq = which == 0 ? q2 : k2;
  float bv4[4];
#pragma unroll
  for (int j = 0; j < 4; ++j) bv4[j] = bias[nt + wn * 64 + j * 16 + lr];

#pragma unroll
  for (int i = 0; i < 8; ++i) {
#pragma unroll
    for (int r = 0; r < 4; ++r) {
      const int g = mt + wm * 128 + i * 16 + q * 4 + r;
      const int t = g >> 3, b = g & 7;
      float ss = 0.f;
#pragma unroll
      for (int j = 0; j < 4; ++j) {
        const float val = acc[i][j][r] + bv4[j];
        dst[(size_t)(b * S_LEN + t) * EMB + nc0 + wn * 64 + j * 16 + lr] = f2bf(val);
        ss += val * val;
      }
      if (which < 2) {
        ss += __shfl_xor(ss, 1);
        ss += __shfl_xor(ss, 2);
        ss += __shfl_xor(ss, 4);
        ss += __shfl_xor(ss, 8);
        if (lr == 0) atomicAdd(&sq[b * S_LEN + t], ss);
      }
    }
  }
}

// ---------- transpose V[b][j][e] -> Vt[b][e][j] ----------
__global__ __launch_bounds__(256) void k_transpose(const ushort_t* __restrict__ V,
                                                   ushort_t* __restrict__ Vt) {
  __shared__ ushort_t tile[64][72];
  const int b = blockIdx.z, j0 = blockIdx.x * 64, e0 = blockIdx.y * 64;
  const ushort_t* src = V + ((size_t)b * S_LEN + j0) * EMB + e0;
  const int tid = threadIdx.x;
#pragma unroll
  for (int rep = 0; rep < 2; ++rep) {
    const int lin = rep * 256 + tid;
    const int j = lin >> 3, e8 = (lin & 7) * 8;
    *(uint4*)&tile[j][e8] = *(const uint4*)(src + (size_t)j * EMB + e8);
  }
  __syncthreads();
  ushort_t* dst = Vt + ((size_t)b * EMB + e0) * S_LEN + j0;
#pragma unroll
  for (int rep = 0; rep < 2; ++rep) {
    const int lin = rep * 256 + tid;
    const int e = lin >> 3, j8 = (lin & 7) * 8;
    ushort8 o;
#pragma unroll
    for (int m = 0; m < 8; ++m) o[m] = tile[j8 + m][e];
    *(ushort8*)(dst + (size_t)e * S_LEN + j8) = o;
  }
}

// ---------- GEMM 2: logits + exp (per batch: 2048 x 2048 x 1024) ----------
__global__ __launch_bounds__(512, 2) void k_logits(
    const ushort_t* __restrict__ Q, const ushort_t* __restrict__ Kp,
    const float* __restrict__ q2, const float* __restrict__ k2,
    ushort_t* __restrict__ P, float* __restrict__ rsum) {
  __shared__ __attribute__((aligned(16))) ushort_t smem[65536];
  const int b = blockIdx.z;
  const int mt = blockIdx.x * 256, nt = blockIdx.y * 256;
  floatx4 acc[8][4];
  const floatx4 z = {0.f, 0.f, 0.f, 0.f};
#pragma unroll
  for (int i = 0; i < 8; ++i)
#pragma unroll
    for (int j = 0; j < 4; ++j) acc[i][j] = z;

  gemm8_core(Q + ((size_t)b * S_LEN + mt) * EMB,
             Kp + ((size_t)b * S_LEN + nt) * EMB, EMB, EMB, EMB, smem, acc);

  const int lane = threadIdx.x & 63, wave = threadIdx.x >> 6;
  const int wm = wave >> 2, wn = wave & 3;
  const int lr = lane & 15, q = lane >> 4;
  float k2v[4];
#pragma unroll
  for (int j = 0; j < 4; ++j) k2v[j] = k2[b * S_LEN + nt + wn * 64 + j * 16 + lr];

#pragma unroll
  for (int i = 0; i < 8; ++i) {
#pragma unroll
    for (int r = 0; r < 4; ++r) {
      const int t = mt + wm * 128 + i * 16 + q * 4 + r;
      const float q2v = q2[b * S_LEN + t];
      float ss = 0.f;
#pragma unroll
      for (int j = 0; j < 4; ++j) {
        float d2 = q2v + k2v[j] - 2.f * acc[i][j][r];
        d2 = fmaxf(d2, 0.f);
        const float p = __expf(-GAMMA * d2);
        P[((size_t)b * S_LEN + t) * S_LEN + nt + wn * 64 + j * 16 + lr] = f2bf(p);
        ss += p;
      }
      ss += __shfl_xor(ss, 1);
      ss += __shfl_xor(ss, 2);
      ss += __shfl_xor(ss, 4);
      ss += __shfl_xor(ss, 8);
      if (lr == 0) atomicAdd(&rsum[b * S_LEN + t], ss);
    }
  }
}

// ---------- GEMM 3: O = (P @ V) / rowsum (per batch: 2048 x 1024 x 2048) ----------
__global__ __launch_bounds__(512, 2) void k_out(
    const ushort_t* __restrict__ P, const ushort_t* __restrict__ Vt,
    const float* __restrict__ rsum, float* __restrict__ out) {
  __shared__ __attribute__((aligned(16))) ushort_t smem[65536];
  const int b = blockIdx.z;
  const int mt = blockIdx.x * 256, nt = blockIdx.y * 256;
  floatx4 acc[8][4];
  const floatx4 z = {0.f, 0.f, 0.f, 0.f};
#pragma unroll
  for (int i = 0; i < 8; ++i)
#pragma unroll
    for (int j = 0; j < 4; ++j) acc[i][j] = z;

  gemm8_core(P + ((size_t)b * S_LEN + mt) * S_LEN,
             Vt + ((size_t)b * EMB + nt) * S_LEN, S_LEN, S_LEN, S_LEN, smem, acc);

  const int lane = threadIdx.x & 63, wave = threadIdx.x >> 6;
  const int wm = wave >> 2, wn = wave & 3;
  const int lr = lane & 15, q = lane >> 4;
#pragma unroll
  for (int i = 0; i < 8; ++i) {
#pragma unroll
    for (int r = 0; r < 4; ++r) {
      const int t = mt + wm * 128 + i * 16 + q * 4 + r;
      const float rinv = 1.f / rsum[b * S_LEN + t];
#pragma unroll
      for (int j = 0; j < 4; ++j) {
        const int e = nt + wn * 64 + j * 16 + lr;
        out[((size_t)t * BATCH + b) * EMB + e] = acc[i][j][r] * rinv;
      }
    }
  }
}

extern "C" void kernel_launch(void* const* d_in, const int* in_sizes, int n_in,
                              void* d_out, int out_size, void* d_ws, size_t ws_size,
                              hipStream_t stream) {
  (void)in_sizes; (void)n_in; (void)out_size; (void)ws_size;
  const float* X  = (const float*)d_in[0];
  const float* Wq = (const float*)d_in[1];
  const float* bq = (const float*)d_in[2];
  const float* Wk = (const float*)d_in[3];
  const float* bk = (const float*)d_in[4];
  const float* Wv = (const float*)d_in[5];
  const float* bv = (const float*)d_in[6];
  float* out = (float*)d_out;
  char* ws = (char*)d_ws;

  // workspace layout (bytes); Xb aliases P (Xb dead before P is written)
  ushort_t* Q    = (ushort_t*)(ws + 0);           //  33,554,432
  ushort_t* Kp   = (ushort_t*)(ws + 33554432);    //  33,554,432
  ushort_t* V    = (ushort_t*)(ws + 67108864);    //  33,554,432
  ushort_t* Vt   = (ushort_t*)(ws + 100663296);   //  33,554,432
  ushort_t* P    = (ushort_t*)(ws + 134217728);   //  67,108,864
  ushort_t* Xb   = (ushort_t*)(ws + 134217728);   //  alias of P[0:33.5M]
  ushort_t* Wqkv = (ushort_t*)(ws + 201326592);   //   6,291,456
  float*    bias = (float*)(ws + 207618048);      //      12,288
  float*    q2   = (float*)(ws + 207630336);      //      65,536
  float*    k2   = (float*)(ws + 207695872);      //      65,536
  float*    rsum = (float*)(ws + 207761408);      //      65,536  -> total ~198 MiB

  k_quant_x <<<16384, 256, 0, stream>>>(X, Xb);
  k_quant_w <<<3072, 256, 0, stream>>>(Wq, Wk, Wv, Wqkv);
  k_bias_zero<<<64, 256, 0, stream>>>(bq, bk, bv, bias, q2, k2, rsum);
  k_gemm_qkv<<<dim3(64, 12), 512, 0, stream>>>(Xb, Wqkv, bias, Q, Kp, V, q2, k2);
  k_transpose<<<dim3(32, 16, 8), 256, 0, stream>>>(V, Vt);
  k_logits  <<<dim3(8, 8, 8), 512, 0, stream>>>(Q, Kp, q2, k2, P, rsum);
  k_out     <<<dim3(8, 4, 8), 512, 0, stream>>>(P, Vt, rsum, out);
}

// Round 7
// 399.839 us; speedup vs baseline: 1.0098x; 1.0098x over previous
//
#include <hip/hip_runtime.h>
#include <stdint.h>

#define S_LEN 2048
#define BATCH 8
#define EMB   1024
#define GAMMA 0.5f

typedef unsigned short ushort_t;
typedef __attribute__((ext_vector_type(8))) short  short8;
typedef __attribute__((ext_vector_type(8))) unsigned short ushort8;
typedef __attribute__((ext_vector_type(4))) float  floatx4;

__device__ __forceinline__ ushort_t f2bf(float f) {
  uint32_t x = __float_as_uint(f);
  x += 0x7fffu + ((x >> 16) & 1u);   // round-to-nearest-even
  return (ushort_t)(x >> 16);
}

__device__ __forceinline__ void gl_lds16(const ushort_t* g, ushort_t* l) {
  __builtin_amdgcn_global_load_lds(
      (const __attribute__((address_space(1))) unsigned int*)g,
      (__attribute__((address_space(3))) unsigned int*)l, 16, 0, 0);
}

// ---------------------------------------------------------------------------
// 256x256-tile 8-wave pipelined NT bf16 GEMM core (C = A * B^T, K-contig).
// BK=64 as two 32-wide kslices; LDS regions (ushort offsets, per buffer):
//   As0 +0 | As1 +8192 | Bs0 +16384 | Bs1 +24576 ; regions 256r x 32 bf16.
// Double buffered = 128 KiB. Swizzle: slot ^= (row>>1)&3 on both the
// pre-swizzled global source and the ds_read address (R3, conflict-free).
//
// R7 = R6 with the prologue seeding bug fixed: the loop stages As1 only at
// distance kt+2 (I_3), so the prologue MUST stage SEVEN halves including
// As1(1) (the R6 NaN was As1(1) never staged). Prologue drain = vmcnt(6)
// (keep As0/Bs0/As1(1); kt0's four regions land).
//
// Fences (R6 design, ledger re-verified): interval END =
//   [counted vmcnt if due][lgkmcnt(0)][s_barrier][""-asm memory wall]
//   - WAR: reads drain at own-interval lgkm0 BEFORE the barrier; every stage
//     to that region is >=1 barrier later (earlier drain than R4 -> safer).
//   - RAW: staged regions are read only after counted vmcnt -> barrier
//     (I_2-end vmcnt(4) drains through Bs1(kt+1) incl. As1(kt+1); tail
//     vmcnt(0) at kt=NT-2). ""-wall stops read hoisting above the barrier.
//   - NO sched_barrier(0), NO forced drain at interval open (m141 lesson):
//     compiler emits fine-grained per-MFMA lgkmcnt waits itself.
// Stage addressing: per-lane global base pointers hoisted; inner loop adds
// a 32-bit element offset only (cuts 64-bit VALU mul chains).
// ---------------------------------------------------------------------------

__device__ __forceinline__ short8 lds_frag(const ushort_t* region, int row, int q) {
  return *(const short8*)(region + row * 32 + (((q ^ (row >> 1)) & 3) << 3));
}

#define MFMA_16(AR, B0, B1, J0, J1)                                            \
  _Pragma("unroll")                                                            \
  for (int i = 0; i < 8; ++i) {                                                \
    acc[i][J0] = __builtin_amdgcn_mfma_f32_16x16x32_bf16(AR[i], B0, acc[i][J0], 0, 0, 0); \
    acc[i][J1] = __builtin_amdgcn_mfma_f32_16x16x32_bf16(AR[i], B1, acc[i][J1], 0, 0, 0); \
  }

#define PHASE_END()                                                            \
  asm volatile("s_waitcnt lgkmcnt(0)" ::: "memory");                           \
  __builtin_amdgcn_s_barrier();                                                \
  asm volatile("" ::: "memory");

__device__ __forceinline__ void gemm8_core(
    const ushort_t* __restrict__ A, const ushort_t* __restrict__ B,
    int lda, int ldb, int K, ushort_t* smem, floatx4 (&acc)[8][4])
{
  const int tid = threadIdx.x;
  const int wave = tid >> 6, lane = tid & 63;
  const int wm = wave >> 2, wn = wave & 3;      // 2 (M) x 4 (N) wave grid
  const int lr = lane & 15, q = lane >> 4;
  const int NT = K >> 6;
  const int ra = wm * 128 + lr;   // wave's A-row base
  const int rb = wn * 64 + lr;    // wave's B-row base
  const int r4 = lane >> 2;
  const int slot = (lane & 3) ^ ((r4 >> 1) & 3);   // source pre-swizzle
  ushort_t* const lw = smem + wave * 1024;         // wave's slice of a region

  // Hoisted per-lane global stage pointers; inner loop adds 32-bit koff.
  const ushort_t* pA0 = A + (size_t)(wave * 32 + r4) * lda + slot * 8;
  const ushort_t* pA1 = pA0 + (size_t)16 * lda;
  const ushort_t* pB0 = B + (size_t)(wave * 32 + r4) * ldb + slot * 8;
  const ushort_t* pB1 = pB0 + (size_t)16 * ldb;

  auto stA = [&](int regionOff, int koff) {
    gl_lds16(pA0 + koff, lw + regionOff);
    gl_lds16(pA1 + koff, lw + regionOff + 512);
  };
  auto stB = [&](int regionOff, int koff) {
    gl_lds16(pB0 + koff, lw + regionOff);
    gl_lds16(pB1 + koff, lw + regionOff + 512);
  };

  // Prologue: SEVEN halves = all of kt0 + As0(1),Bs0(1),As1(1); drain kt0 (8).
  stA(0, 0);      stB(16384, 0);
  stA(8192, 32);  stB(24576, 32);
  stA(32768, 64); stB(49152, 64);
  stA(40960, 96);                                   // As1(1) — loop never stages it
  asm volatile("s_waitcnt vmcnt(6)" ::: "memory");  // keep As0/Bs0/As1(1)
  __builtin_amdgcn_s_barrier();
  asm volatile("" ::: "memory");

  short8 ar[8], ar2[8], b0, b1, t0, t1, u0, u1;
#pragma unroll
  for (int i = 0; i < 8; ++i) ar[i] = lds_frag(smem, ra + i * 16, q);
  b0 = lds_frag(smem + 16384, rb,      q);
  b1 = lds_frag(smem + 16384, rb + 16, q);

  for (int kt = 0; kt < NT; ++kt) {
    const int bo = (kt & 1) * 32768;
    const int bn = bo ^ 32768;
    ushort_t* const cur = smem + bo;
    ushort_t* const nxt = smem + bn;
    const bool s1 = (kt + 1) < NT, s2 = (kt + 2) < NT;
    const int k1 = (kt + 1) << 6, k2 = (kt + 2) << 6;

    // ---- I_0: reads {Bs0 r32/48, As1 0..3}; stage Bs1(kt+1); MFMA s0 nf01
    t0 = lds_frag(cur + 16384, rb + 32, q);
    t1 = lds_frag(cur + 16384, rb + 48, q);
#pragma unroll
    for (int i = 0; i < 4; ++i) ar2[i] = lds_frag(cur + 8192, ra + i * 16, q);
    if (s1) stB(bn + 24576, k1 + 32);
    __builtin_amdgcn_s_setprio(1);
    MFMA_16(ar, b0, b1, 0, 1)
    __builtin_amdgcn_s_setprio(0);
    PHASE_END()

    // ---- I_1: reads {As1 4..7, Bs1 r0/16}; stage As0(kt+2); MFMA s0 nf23
#pragma unroll
    for (int i = 4; i < 8; ++i) ar2[i] = lds_frag(cur + 8192, ra + i * 16, q);
    u0 = lds_frag(cur + 24576, rb,      q);
    u1 = lds_frag(cur + 24576, rb + 16, q);
    if (s2) stA(bo, k2);
    __builtin_amdgcn_s_setprio(1);
    MFMA_16(ar, t0, t1, 2, 3)
    __builtin_amdgcn_s_setprio(0);
    PHASE_END()

    // ---- I_2: reads {Bs1 r32/48}; stage Bs0(kt+2); MFMA s1 nf01; vmcnt(4)
    t0 = lds_frag(cur + 24576, rb + 32, q);
    t1 = lds_frag(cur + 24576, rb + 48, q);
    if (s2) stB(bo + 16384, k2);
    __builtin_amdgcn_s_setprio(1);
    MFMA_16(ar2, u0, u1, 0, 1)
    __builtin_amdgcn_s_setprio(0);
    if (s2)      { asm volatile("s_waitcnt vmcnt(4)" ::: "memory"); }
    else if (s1) { asm volatile("s_waitcnt vmcnt(0)" ::: "memory"); }
    PHASE_END()

    // ---- I_3: reads next-kt {As0 x8, Bs0 r0/16} from nxt; stage As1(kt+2); MFMA s1 nf23
    if (s1) {
#pragma unroll
      for (int i = 0; i < 8; ++i) ar[i] = lds_frag(nxt, ra + i * 16, q);
      b0 = lds_frag(nxt + 16384, rb,      q);
      b1 = lds_frag(nxt + 16384, rb + 16, q);
    }
    if (s2) stA(bo + 8192, k2 + 32);
    __builtin_amdgcn_s_setprio(1);
    MFMA_16(ar2, t0, t1, 2, 3)
    __builtin_amdgcn_s_setprio(0);
    PHASE_END()
  }
}

// ---------- quantize / pack ----------
__global__ __launch_bounds__(256) void k_quant_x(const float* __restrict__ X,
                                                 ushort_t* __restrict__ Xb) {
  size_t i = ((size_t)blockIdx.x * 256 + threadIdx.x) * 4;
  float4 v = *(const float4*)(X + i);
  *(ushort4*)(Xb + i) = make_ushort4(f2bf(v.x), f2bf(v.y), f2bf(v.z), f2bf(v.w));
}

__global__ __launch_bounds__(256) void k_quant_w(
    const float* __restrict__ Wq, const float* __restrict__ Wk,
    const float* __restrict__ Wv, ushort_t* __restrict__ W) {
  size_t i = ((size_t)blockIdx.x * 256 + threadIdx.x) * 4;
  int row = (int)(i >> 10), col = (int)(i & 1023);
  int sel = row >> 10, sr = row & 1023;
  const float* src = sel == 0 ? Wq : (sel == 1 ? Wk : Wv);
  float4 v = *(const float4*)(src + (size_t)sr * 1024 + col);
  *(ushort4*)(W + i) = make_ushort4(f2bf(v.x), f2bf(v.y), f2bf(v.z), f2bf(v.w));
}

__global__ __launch_bounds__(256) void k_bias_zero(
    const float* __restrict__ bq, const float* __restrict__ bk,
    const float* __restrict__ bv, float* __restrict__ bias,
    float* __restrict__ q2, float* __restrict__ k2, float* __restrict__ rsum) {
  int i = blockIdx.x * 256 + threadIdx.x;
  if (i < 1024)       bias[i] = bq[i];
  else if (i < 2048)  bias[i] = bk[i - 1024];
  else if (i < 3072)  bias[i] = bv[i - 2048];
  if (i < BATCH * S_LEN) { q2[i] = 0.f; k2[i] = 0.f; rsum[i] = 0.f; }
}

// ---------- GEMM 1: QKV projection (M=16384, N=3072, K=1024) ----------
__global__ __launch_bounds__(512, 2) void k_gemm_qkv(
    const ushort_t* __restrict__ Xb, const ushort_t* __restrict__ W,
    const float* __restrict__ bias,
    ushort_t* __restrict__ Q, ushort_t* __restrict__ Kp, ushort_t* __restrict__ V,
    float* __restrict__ q2, float* __restrict__ k2) {
  __shared__ __attribute__((aligned(16))) ushort_t smem[65536];
  // XCD swizzle (T1): lin%8 = XCD -> give each XCD 8 consecutive mt panels
  // (4 MB of X, L2-resident; X fetched once per XCD), nt sweeps slowest.
  const int lin = blockIdx.x + (blockIdx.y << 6);        // 0..767
  const int mt_i = (lin & 7) * 8 + ((lin >> 3) & 7);     // 0..63
  const int nt_i = lin >> 6;                             // 0..11
  const int mt = mt_i * 256, nt = nt_i * 256;
  floatx4 acc[8][4];
  const floatx4 z = {0.f, 0.f, 0.f, 0.f};
#pragma unroll
  for (int i = 0; i < 8; ++i)
#pragma unroll
    for (int j = 0; j < 4; ++j) acc[i][j] = z;

  gemm8_core(Xb + (size_t)mt * EMB, W + (size_t)nt * EMB, EMB, EMB, EMB, smem, acc);

  const int lane = threadIdx.x & 63, wave = threadIdx.x >> 6;
  const int wm = wave >> 2, wn = wave & 3;
  const int lr = lane & 15, q = lane >> 4;
  const int which = nt >> 10;        // 0=q 1=k 2=v  (256 | 1024 so no straddle)
  const int nc0 = nt & 1023;
  ushort_t* dst = which == 0 ? Q : (which == 1 ? Kp : V);
  float* sq = which == 0 ? q2 : k2;
  float bv4[4];
#pragma unroll
  for (int j = 0; j < 4; ++j) bv4[j] = bias[nt + wn * 64 + j * 16 + lr];

#pragma unroll
  for (int i = 0; i < 8; ++i) {
#pragma unroll
    for (int r = 0; r < 4; ++r) {
      const int g = mt + wm * 128 + i * 16 + q * 4 + r;
      const int t = g >> 3, b = g & 7;
      float ss = 0.f;
#pragma unroll
      for (int j = 0; j < 4; ++j) {
        const float val = acc[i][j][r] + bv4[j];
        dst[(size_t)(b * S_LEN + t) * EMB + nc0 + wn * 64 + j * 16 + lr] = f2bf(val);
        ss += val * val;
      }
      if (which < 2) {
        ss += __shfl_xor(ss, 1);
        ss += __shfl_xor(ss, 2);
        ss += __shfl_xor(ss, 4);
        ss += __shfl_xor(ss, 8);
        if (lr == 0) atomicAdd(&sq[b * S_LEN + t], ss);
      }
    }
  }
}

// ---------- transpose V[b][j][e] -> Vt[b][e][j] ----------
__global__ __launch_bounds__(256) void k_transpose(const ushort_t* __restrict__ V,
                                                   ushort_t* __restrict__ Vt) {
  __shared__ ushort_t tile[64][72];
  const int b = blockIdx.z, j0 = blockIdx.x * 64, e0 = blockIdx.y * 64;
  const ushort_t* src = V + ((size_t)b * S_LEN + j0) * EMB + e0;
  const int tid = threadIdx.x;
#pragma unroll
  for (int rep = 0; rep < 2; ++rep) {
    const int lin = rep * 256 + tid;
    const int j = lin >> 3, e8 = (lin & 7) * 8;
    *(uint4*)&tile[j][e8] = *(const uint4*)(src + (size_t)j * EMB + e8);
  }
  __syncthreads();
  ushort_t* dst = Vt + ((size_t)b * EMB + e0) * S_LEN + j0;
#pragma unroll
  for (int rep = 0; rep < 2; ++rep) {
    const int lin = rep * 256 + tid;
    const int e = lin >> 3, j8 = (lin & 7) * 8;
    ushort8 o;
#pragma unroll
    for (int m = 0; m < 8; ++m) o[m] = tile[j8 + m][e];
    *(ushort8*)(dst + (size_t)e * S_LEN + j8) = o;
  }
}

// ---------- GEMM 2: logits + exp (per batch: 2048 x 2048 x 1024) ----------
__global__ __launch_bounds__(512, 2) void k_logits(
    const ushort_t* __restrict__ Q, const ushort_t* __restrict__ Kp,
    const float* __restrict__ q2, const float* __restrict__ k2,
    ushort_t* __restrict__ P, float* __restrict__ rsum) {
  __shared__ __attribute__((aligned(16))) ushort_t smem[65536];
  // XCD swizzle: pin each batch to one XCD (Q/K panels L2-cycled per XCD).
  const int lin = blockIdx.x + (blockIdx.y << 3) + (blockIdx.z << 6);  // 0..511
  const int b = lin & 7;
  const int seq = lin >> 3;                    // 0..63
  const int mt = (seq & 7) * 256, nt = (seq >> 3) * 256;
  floatx4 acc[8][4];
  const floatx4 z = {0.f, 0.f, 0.f, 0.f};
#pragma unroll
  for (int i = 0; i < 8; ++i)
#pragma unroll
    for (int j = 0; j < 4; ++j) acc[i][j] = z;

  gemm8_core(Q + ((size_t)b * S_LEN + mt) * EMB,
             Kp + ((size_t)b * S_LEN + nt) * EMB, EMB, EMB, EMB, smem, acc);

  const int lane = threadIdx.x & 63, wave = threadIdx.x >> 6;
  const int wm = wave >> 2, wn = wave & 3;
  const int lr = lane & 15, q = lane >> 4;
  float k2v[4];
#pragma unroll
  for (int j = 0; j < 4; ++j) k2v[j] = k2[b * S_LEN + nt + wn * 64 + j * 16 + lr];

#pragma unroll
  for (int i = 0; i < 8; ++i) {
#pragma unroll
    for (int r = 0; r < 4; ++r) {
      const int t = mt + wm * 128 + i * 16 + q * 4 + r;
      const float q2v = q2[b * S_LEN + t];
      float ss = 0.f;
#pragma unroll
      for (int j = 0; j < 4; ++j) {
        float d2 = q2v + k2v[j] - 2.f * acc[i][j][r];
        d2 = fmaxf(d2, 0.f);
        const float p = __expf(-GAMMA * d2);
        P[((size_t)b * S_LEN + t) * S_LEN + nt + wn * 64 + j * 16 + lr] = f2bf(p);
        ss += p;
      }
      ss += __shfl_xor(ss, 1);
      ss += __shfl_xor(ss, 2);
      ss += __shfl_xor(ss, 4);
      ss += __shfl_xor(ss, 8);
      if (lr == 0) atomicAdd(&rsum[b * S_LEN + t], ss);
    }
  }
}

// ---------- GEMM 3: O = (P @ V) / rowsum (per batch: 2048 x 1024 x 2048) ----------
__global__ __launch_bounds__(512, 2) void k_out(
    const ushort_t* __restrict__ P, const ushort_t* __restrict__ Vt,
    const float* __restrict__ rsum, float* __restrict__ out) {
  __shared__ __attribute__((aligned(16))) ushort_t smem[65536];
  // XCD swizzle: batch-per-XCD (Vt[b] = 4 MB, L2-resident per XCD).
  const int lin = blockIdx.x + (blockIdx.y << 3) + (blockIdx.z << 5);  // 0..255
  const int b = lin & 7;
  const int seq = lin >> 3;                    // 0..31
  const int mt = (seq & 7) * 256, nt = (seq >> 3) * 256;
  floatx4 acc[8][4];
  const floatx4 z = {0.f, 0.f, 0.f, 0.f};
#pragma unroll
  for (int i = 0; i < 8; ++i)
#pragma unroll
    for (int j = 0; j < 4; ++j) acc[i][j] = z;

  gemm8_core(P + ((size_t)b * S_LEN + mt) * S_LEN,
             Vt + ((size_t)b * EMB + nt) * S_LEN, S_LEN, S_LEN, S_LEN, smem, acc);

  const int lane = threadIdx.x & 63, wave = threadIdx.x >> 6;
  const int wm = wave >> 2, wn = wave & 3;
  const int lr = lane & 15, q = lane >> 4;
#pragma unroll
  for (int i = 0; i < 8; ++i) {
#pragma unroll
    for (int r = 0; r < 4; ++r) {
      const int t = mt + wm * 128 + i * 16 + q * 4 + r;
      const float rinv = 1.f / rsum[b * S_LEN + t];
#pragma unroll
      for (int j = 0; j < 4; ++j) {
        const int e = nt + wn * 64 + j * 16 + lr;
        out[((size_t)t * BATCH + b) * EMB + e] = acc[i][j][r] * rinv;
      }
    }
  }
}

extern "C" void kernel_launch(void* const* d_in, const int* in_sizes, int n_in,
                              void* d_out, int out_size, void* d_ws, size_t ws_size,
                              hipStream_t stream) {
  (void)in_sizes; (void)n_in; (void)out_size; (void)ws_size;
  const float* X  = (const float*)d_in[0];
  const float* Wq = (const float*)d_in[1];
  const float* bq = (const float*)d_in[2];
  const float* Wk = (const float*)d_in[3];
  const float* bk = (const float*)d_in[4];
  const float* Wv = (const float*)d_in[5];
  const float* bv = (const float*)d_in[6];
  float* out = (float*)d_out;
  char* ws = (char*)d_ws;

  // workspace layout (bytes); Xb aliases P (Xb dead before P is written)
  ushort_t* Q    = (ushort_t*)(ws + 0);           //  33,554,432
  ushort_t* Kp   = (ushort_t*)(ws + 33554432);    //  33,554,432
  ushort_t* V    = (ushort_t*)(ws + 67108864);    //  33,554,432
  ushort_t* Vt   = (ushort_t*)(ws + 100663296);   //  33,554,432
  ushort_t* P    = (ushort_t*)(ws + 134217728);   //  67,108,864
  ushort_t* Xb   = (ushort_t*)(ws + 134217728);   //  alias of P[0:33.5M]
  ushort_t* Wqkv = (ushort_t*)(ws + 201326592);   //   6,291,456
  float*    bias = (float*)(ws + 207618048);      //      12,288
  float*    q2   = (float*)(ws + 207630336);      //      65,536
  float*    k2   = (float*)(ws + 207695872);      //      65,536
  float*    rsum = (float*)(ws + 207761408);      //      65,536  -> total ~198 MiB

  k_quant_x <<<16384, 256, 0, stream>>>(X, Xb);
  k_quant_w <<<3072, 256, 0, stream>>>(Wq, Wk, Wv, Wqkv);
  k_bias_zero<<<64, 256, 0, stream>>>(bq, bk, bv, bias, q2, k2, rsum);
  k_gemm_qkv<<<dim3(64, 12), 512, 0, stream>>>(Xb, Wqkv, bias, Q, Kp, V, q2, k2);
  k_transpose<<<dim3(32, 16, 8), 256, 0, stream>>>(V, Vt);
  k_logits  <<<dim3(8, 8, 8), 512, 0, stream>>>(Q, Kp, q2, k2, P, rsum);
  k_out     <<<dim3(8, 4, 8), 512, 0, stream>>>(P, Vt, rsum, out);
}